// Round 1
// baseline (79.973 us; speedup 1.0000x reference)
//
#include <hip/hip_runtime.h>
#include <math.h>

#define N_LAYERS 2

// Apply RX mixing [[c, -i s],[-i s, c]] to complex pair (a,b); each float2 = (re, im).
__device__ __forceinline__ void rx_pair(float2& a, float2& b, float c, float s) {
    float2 na = make_float2(fmaf(c, a.x,  s * b.y), fmaf(c, a.y, -s * b.x));
    float2 nb = make_float2(fmaf(s, a.y,  c * b.x), fmaf(-s, a.x, c * b.y));
    a = na; b = nb;
}

// Single-thread precompute: build the fixed layer unitary U (4x4 complex),
// form M = U^dag P0 U restricted entries, fold the initial-state phases
// (1, -i, -i, -1) into a real symmetric N, then collapse N onto the
// (1, cosX0, sinX0) x (1, cosX1, sinX1) bilinear basis -> 9 floats K.
__global__ void qnet_precompute_K(const float* __restrict__ w, float* __restrict__ K) {
    if (threadIdx.x != 0 || blockIdx.x != 0) return;

    float2 U[4][4];  // U[col][row] : column j = circuit applied to basis state e_j
    for (int j = 0; j < 4; ++j)
        for (int r = 0; r < 4; ++r)
            U[j][r] = make_float2(j == r ? 1.f : 0.f, 0.f);

    for (int l = 0; l < N_LAYERS; ++l) {
        float t0 = 0.5f * w[2 * l + 0];
        float t1 = 0.5f * w[2 * l + 1];
        float c0 = cosf(t0), s0 = sinf(t0);
        float c1 = cosf(t1), s1 = sinf(t1);
        for (int j = 0; j < 4; ++j) {
            // RX on qubit0: mixes flat indices (0,2) and (1,3)  [idx = 2*q0 + q1]
            rx_pair(U[j][0], U[j][2], c0, s0);
            rx_pair(U[j][1], U[j][3], c0, s0);
            // RX on qubit1: mixes (0,1) and (2,3)
            rx_pair(U[j][0], U[j][1], c1, s1);
            rx_pair(U[j][2], U[j][3], c1, s1);
            // CNOT(control=q0, target=q1): swap indices 2 and 3
            float2 tmp = U[j][2]; U[j][2] = U[j][3]; U[j][3] = tmp;
        }
    }

    // M_jk = sum_{m in {0,1}} conj(U[j][m]) * U[k][m]   (P0 projects onto rows 0,1)
    float Mre[4][4], Mim[4][4];
    for (int j = 0; j < 4; ++j)
        for (int k = 0; k < 4; ++k) {
            float re = 0.f, im = 0.f;
            for (int m = 0; m < 2; ++m) {
                re += U[j][m].x * U[k][m].x + U[j][m].y * U[k][m].y;
                im += U[j][m].x * U[k][m].y - U[j][m].y * U[k][m].x;
            }
            Mre[j][k] = re; Mim[j][k] = im;
        }

    // Phases of initial state psi = (a, -i b, -i c, -d): phi = (1, -i, -i, -1).
    // N_jk = Re(M_jk * conj(phi_j) * phi_k)
    float N00 = Mre[0][0], N11 = Mre[1][1], N22 = Mre[2][2], N33 = Mre[3][3];
    float N01 = Mim[0][1];   // phase -i -> Im
    float N23 = Mim[2][3];   // phase -i -> Im
    float N02 = Mim[0][2];   // phase -i -> Im
    float N13 = Mim[1][3];   // phase -i -> Im
    float N03 = -Mre[0][3];  // phase -1 -> -Re
    float N12 = Mre[1][2];   // phase +1 -> Re

    K[0] = 0.25f * (N00 + N11 + N22 + N33);  // 1
    K[1] = 0.25f * (N00 - N11 + N22 - N33);  // X1
    K[2] = 0.50f * (N01 + N23);              // S1
    K[3] = 0.25f * (N00 + N11 - N22 - N33);  // X0
    K[4] = 0.25f * (N00 - N11 - N22 + N33);  // X0*X1
    K[5] = 0.50f * (N01 - N23);              // X0*S1
    K[6] = 0.50f * (N02 + N13);              // S0
    K[7] = 0.50f * (N02 - N13);              // S0*X1
    K[8] = 0.50f * (N03 + N12);              // S0*S1
}

__device__ __forceinline__ float qnet_eval1(float x0, float x1,
                                            float k0, float k1, float k2,
                                            float k3, float k4, float k5,
                                            float k6, float k7, float k8) {
    float X0 = __cosf(x0), S0 = __sinf(x0);
    float X1 = __cosf(x1), S1 = __sinf(x1);
    float t0 = fmaf(k2, S1, fmaf(k1, X1, k0));
    float t1 = fmaf(k5, S1, fmaf(k4, X1, k3));
    float t2 = fmaf(k8, S1, fmaf(k7, X1, k6));
    return fmaf(S0, t2, fmaf(X0, t1, t0));
}

// Each thread handles 2 samples: one float4 load (x0a,x1a,x0b,x1b), one float2 store.
__global__ __launch_bounds__(256) void qnet_eval_kernel(
    const float4* __restrict__ x, const float* __restrict__ K,
    float2* __restrict__ out, int n2) {
    int i = blockIdx.x * blockDim.x + threadIdx.x;
    float k0 = K[0], k1 = K[1], k2 = K[2];
    float k3 = K[3], k4 = K[4], k5 = K[5];
    float k6 = K[6], k7 = K[7], k8 = K[8];
    if (i >= n2) return;
    float4 xv = x[i];
    float r0 = qnet_eval1(xv.x, xv.y, k0, k1, k2, k3, k4, k5, k6, k7, k8);
    float r1 = qnet_eval1(xv.z, xv.w, k0, k1, k2, k3, k4, k5, k6, k7, k8);
    out[i] = make_float2(r0, r1);
}

extern "C" void kernel_launch(void* const* d_in, const int* in_sizes, int n_in,
                              void* d_out, int out_size, void* d_ws, size_t ws_size,
                              hipStream_t stream) {
    const float* x = (const float*)d_in[0];          // [B, 2] float32
    const float* w = (const float*)d_in[1];          // [N_LAYERS, 2] float32
    float* K = (float*)d_ws;                         // 9 floats scratch
    float* out = (float*)d_out;                      // [B] float32

    qnet_precompute_K<<<1, 64, 0, stream>>>(w, K);

    int n2 = in_sizes[0] / 4;                        // threads; 2 samples each
    int blocks = (n2 + 255) / 256;
    qnet_eval_kernel<<<blocks, 256, 0, stream>>>(
        (const float4*)x, K, (float2*)out, n2);
}

// Round 3
// 77.292 us; speedup vs baseline: 1.0347x; 1.0347x over previous
//
#include <hip/hip_runtime.h>
#include <math.h>

#define N_LAYERS 2

typedef float vfloat4 __attribute__((ext_vector_type(4)));  // native vec for nontemporal store

// Apply RX mixing [[c, -i s],[-i s, c]] to complex pair (a,b); each float2 = (re, im).
__device__ __forceinline__ void rx_pair(float2& a, float2& b, float c, float s) {
    float2 na = make_float2(fmaf(c, a.x,  s * b.y), fmaf(c, a.y, -s * b.x));
    float2 nb = make_float2(fmaf(s, a.y,  c * b.x), fmaf(-s, a.x, c * b.y));
    a = na; b = nb;
}

// Build the fixed layer unitary U (4x4 complex), form M = U^dag P0 U, fold the
// initial-state phases (1,-i,-i,-1) into a real symmetric N, then collapse onto
// the (1,cosX0,sinX0) x (1,cosX1,sinX1) bilinear basis -> 9 floats K.
// out(x0,x1) = [1,cos x0,sin x0] . K . [1,cos x1,sin x1]^T
__device__ void compute_K(const float* __restrict__ w, float* __restrict__ K) {
    float2 U[4][4];  // U[col][row]
    for (int j = 0; j < 4; ++j)
        for (int r = 0; r < 4; ++r)
            U[j][r] = make_float2(j == r ? 1.f : 0.f, 0.f);

    for (int l = 0; l < N_LAYERS; ++l) {
        float t0 = 0.5f * w[2 * l + 0];
        float t1 = 0.5f * w[2 * l + 1];
        float c0 = __cosf(t0), s0 = __sinf(t0);
        float c1 = __cosf(t1), s1 = __sinf(t1);
        for (int j = 0; j < 4; ++j) {
            rx_pair(U[j][0], U[j][2], c0, s0);   // RX q0: mixes (0,2),(1,3)
            rx_pair(U[j][1], U[j][3], c0, s0);
            rx_pair(U[j][0], U[j][1], c1, s1);   // RX q1: mixes (0,1),(2,3)
            rx_pair(U[j][2], U[j][3], c1, s1);
            float2 tmp = U[j][2]; U[j][2] = U[j][3]; U[j][3] = tmp;  // CNOT
        }
    }

    float Mre[4][4], Mim[4][4];
    for (int j = 0; j < 4; ++j)
        for (int k = 0; k < 4; ++k) {
            float re = 0.f, im = 0.f;
            for (int m = 0; m < 2; ++m) {   // P0 projects onto rows 0,1
                re += U[j][m].x * U[k][m].x + U[j][m].y * U[k][m].y;
                im += U[j][m].x * U[k][m].y - U[j][m].y * U[k][m].x;
            }
            Mre[j][k] = re; Mim[j][k] = im;
        }

    float N00 = Mre[0][0], N11 = Mre[1][1], N22 = Mre[2][2], N33 = Mre[3][3];
    float N01 = Mim[0][1], N23 = Mim[2][3], N02 = Mim[0][2], N13 = Mim[1][3];
    float N03 = -Mre[0][3], N12 = Mre[1][2];

    K[0] = 0.25f * (N00 + N11 + N22 + N33);  // 1
    K[1] = 0.25f * (N00 - N11 + N22 - N33);  // X1
    K[2] = 0.50f * (N01 + N23);              // S1
    K[3] = 0.25f * (N00 + N11 - N22 - N33);  // X0
    K[4] = 0.25f * (N00 - N11 - N22 + N33);  // X0*X1
    K[5] = 0.50f * (N01 - N23);              // X0*S1
    K[6] = 0.50f * (N02 + N13);              // S0
    K[7] = 0.50f * (N02 - N13);              // S0*X1
    K[8] = 0.50f * (N03 + N12);              // S0*S1
}

__device__ __forceinline__ float qnet_eval1(float x0, float x1,
                                            float k0, float k1, float k2,
                                            float k3, float k4, float k5,
                                            float k6, float k7, float k8) {
    float X0 = __cosf(x0), S0 = __sinf(x0);
    float X1 = __cosf(x1), S1 = __sinf(x1);
    float t0 = fmaf(k2, S1, fmaf(k1, X1, k0));
    float t1 = fmaf(k5, S1, fmaf(k4, X1, k3));
    float t2 = fmaf(k8, S1, fmaf(k7, X1, k6));
    return fmaf(S0, t2, fmaf(X0, t1, t0));
}

// Fused single kernel: each thread handles 4 samples (two float4 loads of x,
// one float4 store). Thread 0 per block computes the 9 K coefficients into LDS
// while the global loads (issued first) are in flight.
__global__ __launch_bounds__(256) void qnet_fused_kernel(
    const float4* __restrict__ x, const float* __restrict__ w,
    vfloat4* __restrict__ out, int nthreads) {
    int i = blockIdx.x * blockDim.x + threadIdx.x;
    bool act = (i < nthreads);

    float4 xa, xb;
    if (act) {                       // issue loads before the K-compute barrier
        xa = x[2 * i + 0];
        xb = x[2 * i + 1];
    }

    __shared__ float Ks[9];
    if (threadIdx.x == 0) compute_K(w, Ks);
    __syncthreads();

    float k0 = Ks[0], k1 = Ks[1], k2 = Ks[2];
    float k3 = Ks[3], k4 = Ks[4], k5 = Ks[5];
    float k6 = Ks[6], k7 = Ks[7], k8 = Ks[8];

    if (act) {
        vfloat4 r;
        r.x = qnet_eval1(xa.x, xa.y, k0, k1, k2, k3, k4, k5, k6, k7, k8);
        r.y = qnet_eval1(xa.z, xa.w, k0, k1, k2, k3, k4, k5, k6, k7, k8);
        r.z = qnet_eval1(xb.x, xb.y, k0, k1, k2, k3, k4, k5, k6, k7, k8);
        r.w = qnet_eval1(xb.z, xb.w, k0, k1, k2, k3, k4, k5, k6, k7, k8);
        __builtin_nontemporal_store(r, &out[i]);
    }
}

extern "C" void kernel_launch(void* const* d_in, const int* in_sizes, int n_in,
                              void* d_out, int out_size, void* d_ws, size_t ws_size,
                              hipStream_t stream) {
    const float* x = (const float*)d_in[0];    // [B, 2] float32
    const float* w = (const float*)d_in[1];    // [N_LAYERS, 2] float32

    int nthreads = in_sizes[0] / 8;            // 4 samples (8 floats of x) per thread
    int blocks = (nthreads + 255) / 256;
    qnet_fused_kernel<<<blocks, 256, 0, stream>>>(
        (const float4*)x, w, (vfloat4*)d_out, nthreads);
}